// Round 10
// baseline (379.548 us; speedup 1.0000x reference)
//
#include <hip/hip_runtime.h>
#include <hip/hip_bf16.h>
#include <stdint.h>

// Problem constants (B=4, S=2048, H=1024, E=8, K=2)
#define E_    8
#define H_    1024
#define NTOK  8192           // B*S
#define KSEL  2
#define NSLOT (NTOK * KSEL)  // 16384

typedef __attribute__((ext_vector_type(8))) short   short8_t;  // 8 bf16 in 4 VGPRs
typedef __attribute__((ext_vector_type(4))) float   f32x4;

// GEMM tiling: 128x128, BK=64, 4 waves. Reg-staged (global->VGPR->ds_write),
// PADDED LDS (stride 72 elems -> conflict-free b128 r/w), TRUE double-buffer
// with ONE raw barrier per K-tile; loads stay in flight across barriers
// (counted vmcnt via data-dep, never drained). 73.7KB LDS -> 2 blocks/CU.
#define BM 128
#define BN 128
#define BK 64
#define LDP 72               // padded row stride (elems); (row+unit)%8 spreads quad-banks
#define MAXMT 136            // ceil-sum of per-expert M-tiles <= 128+7=135
#define NT    (H_ / BN)      // 8 N-tiles
#define NWG   (MAXMT * NT)   // 1088, divisible by 8 (bijective XCD swizzle)

// ---- workspace layout (bytes) ----
#define CNT_OFF   0
#define CUR_OFF   64
#define OFFS_OFF  128
#define TOFF_OFF  256
#define TOK_OFF   1024                     // NSLOT ints
#define WSL_OFF   (TOK_OFF + NSLOT * 4)    // NSLOT floats
#define AG_ROWS   (NSLOT + 256)
#define AG_OFF    (1 << 18)
#define H1_OFF    (AG_OFF + AG_ROWS * H_ * 2)
#define W1T_OFF   (H1_OFF + AG_ROWS * H_ * 2)
#define W2T_OFF   (W1T_OFF + E_ * H_ * H_ * 2)

// ---------------------------------------------------------------------------
__global__ void route_count(const int* __restrict__ idx, int* __restrict__ cnt) {
  int p = blockIdx.x * 256 + threadIdx.x;
  if (p < NSLOT) atomicAdd(&cnt[idx[p]], 1);
}

__global__ void route_scan(const int* __restrict__ cnt, int* __restrict__ offs,
                           int* __restrict__ cur, int* __restrict__ toff) {
  if (threadIdx.x == 0) {
    int s = 0, t = 0;
    for (int e = 0; e < E_; ++e) {
      offs[e] = s; cur[e] = s; toff[e] = t;
      s += cnt[e];
      t += (cnt[e] + BM - 1) / BM;
    }
    offs[E_] = s; toff[E_] = t;
  }
}

__global__ void route_scatter(const int* __restrict__ idx, const float* __restrict__ tkw,
                              int* __restrict__ cur, int* __restrict__ tok,
                              float* __restrict__ wsl) {
  int p = blockIdx.x * 256 + threadIdx.x;
  if (p < NSLOT) {
    int e = idx[p];
    int pos = atomicAdd(&cur[e], 1);
    tok[pos] = p >> 1;
    wsl[pos] = tkw[p];
  }
}

// ---------------------------------------------------------------------------
// wt[e][f][h] = (bf16) w[e][h][f]
__global__ void transpose_cast(const float* __restrict__ w1, const float* __restrict__ w2,
                               __hip_bfloat16* __restrict__ wt1, __hip_bfloat16* __restrict__ wt2) {
  __shared__ float t[32][33];
  const int z = blockIdx.z;
  const float* W = (z < E_ ? w1 : w2) + ((size_t)(z & 7) << 20);
  __hip_bfloat16* WT = (z < E_ ? wt1 : wt2) + ((size_t)(z & 7) << 20);
  const int h0 = blockIdx.y * 32, f0 = blockIdx.x * 32;
  const int tx = threadIdx.x, ty = threadIdx.y;  // 32 x 8
#pragma unroll
  for (int i = 0; i < 32; i += 8)
    t[ty + i][tx] = W[(size_t)(h0 + ty + i) * H_ + f0 + tx];
  __syncthreads();
#pragma unroll
  for (int i = 0; i < 32; i += 8)
    WT[(size_t)(f0 + ty + i) * H_ + h0 + tx] = __float2bfloat16(t[tx][ty + i]);
}

// ---------------------------------------------------------------------------
// Grouped GEMM, dbuf reg-staged, 1 barrier per K-tile.
//   EPI=0: A = gathered f32 x-rows via tok (gather FUSED); h1 = relu(AW^T+b)
//   EPI=1: A = h1 (bf16);  out[tok[p]] += wsl[p]*(AW^T+b) (f32 atomics)
#define FENCE_BAR() do {                                   \
    asm volatile("s_waitcnt lgkmcnt(0)" ::: "memory");     \
    __builtin_amdgcn_s_barrier();                          \
    __builtin_amdgcn_sched_barrier(0);                     \
  } while (0)

template <int EPI>
__launch_bounds__(256, 2)
__global__ void moe_gemm(const float* __restrict__ Xf,            // EPI=0 A source
                         const __hip_bfloat16* __restrict__ Ah,   // EPI=1 A source
                         const __hip_bfloat16* __restrict__ Wt,   // [E][H][H] (f-major)
                         const float* __restrict__ bias,          // [E][H]
                         __hip_bfloat16* __restrict__ h1out,
                         float* __restrict__ out,
                         const int* __restrict__ cnt, const int* __restrict__ offs,
                         const int* __restrict__ toff,
                         const int* __restrict__ tok, const float* __restrict__ wsl) {
  // T1: bijective XCD swizzle (NWG % 8 == 0)
  const int wgid = (blockIdx.x & 7) * (NWG / 8) + (blockIdx.x >> 3);
  const int bt = wgid >> 3;            // flat M-tile id across experts
  const int nt = wgid & 7;             // N-tile
  if (bt >= toff[E_]) return;
  int e = 0;
  while (bt >= toff[e + 1]) ++e;
  const int mt = bt - toff[e];
  const int count = cnt[e];

  const int tid = threadIdx.x;
  const int lane = tid & 63;
  const int wid = tid >> 6;
  const int wm = wid >> 1, wn = wid & 1;  // 2x2 waves -> per-wave 64x64 output
  const int l15 = lane & 15, hi = lane >> 4;

  const size_t Arow0 = (size_t)(offs[e] + mt * BM);
  const __hip_bfloat16* Bexp = Wt + ((size_t)e << 20) + (size_t)(nt * BN) * H_;

  __shared__ __hip_bfloat16 smA[2][BM * LDP];  // 18.4 KB each
  __shared__ __hip_bfloat16 smB[2][BN * LDP];  // 73.7 KB total -> 2 blocks/CU

  // staging map: item i covers rows [i*32, i*32+32); thread -> row i*32+(tid>>3),
  // 16B-unit (tid&7). 8 consecutive lanes cover one contiguous row segment.
  const int srow = tid >> 3;         // 0..31
  const int sun  = (tid & 7) * 8;    // element offset within BK row

  // per-thread A row pointers (loop-invariant)
  const float*          aptrF[4];
  const __hip_bfloat16* aptrH[4];
#pragma unroll
  for (int i = 0; i < 4; ++i) {
    if constexpr (EPI == 0) {
      int p = (int)Arow0 + i * 32 + srow;
      if (p > NSLOT - 1) p = NSLOT - 1;
      aptrF[i] = Xf + (size_t)tok[p] * H_ + sun;
    } else {
      aptrH[i] = Ah + (Arow0 + i * 32 + srow) * H_ + sun;
    }
  }
  const __hip_bfloat16* bptr = Bexp + (size_t)srow * H_ + sun;  // +i*32*H_ per item

  // two named register sets (rule 20: static indexing only)
  f32x4   faX[4][2], faY[4][2];   // EPI=0 A staging (f32)
  short8_t raX[4], raY[4];        // EPI=1 A staging (bf16)
  short8_t rbX[4], rbY[4];

#define LOADSET(S, kt)                                                          \
  do {                                                                          \
    _Pragma("unroll")                                                           \
    for (int i = 0; i < 4; ++i) {                                               \
      if constexpr (EPI == 0) {                                                 \
        const f32x4* ap = (const f32x4*)(aptrF[i] + (kt) * BK);                 \
        fa##S[i][0] = ap[0]; fa##S[i][1] = ap[1];                               \
      } else {                                                                  \
        ra##S[i] = *(const short8_t*)(aptrH[i] + (kt) * BK);                    \
      }                                                                         \
      rb##S[i] = *(const short8_t*)(bptr + (size_t)(i * 32) * H_ + (kt) * BK);  \
    }                                                                           \
  } while (0)

#define WRITESET(S, buf)                                                        \
  do {                                                                          \
    _Pragma("unroll")                                                           \
    for (int i = 0; i < 4; ++i) {                                               \
      short8_t av;                                                              \
      if constexpr (EPI == 0) {                                                 \
        union { __hip_bfloat16 h[8]; short8_t v; } cv;                          \
        _Pragma("unroll")                                                       \
        for (int j = 0; j < 4; ++j) {                                           \
          cv.h[j]     = __float2bfloat16(fa##S[i][0][j]);                       \
          cv.h[4 + j] = __float2bfloat16(fa##S[i][1][j]);                       \
        }                                                                       \
        av = cv.v;                                                              \
      } else {                                                                  \
        av = ra##S[i];                                                          \
      }                                                                         \
      *(short8_t*)&smA[buf][(i * 32 + srow) * LDP + sun] = av;                  \
      *(short8_t*)&smB[buf][(i * 32 + srow) * LDP + sun] = rb##S[i];            \
    }                                                                           \
  } while (0)

  f32x4 acc[4][4];
#pragma unroll
  for (int mi = 0; mi < 4; ++mi)
#pragma unroll
    for (int ni = 0; ni < 4; ++ni) acc[mi][ni] = f32x4{0.f, 0.f, 0.f, 0.f};

  auto compute = [&](int buf) {
#pragma unroll
    for (int ks = 0; ks < 2; ++ks) {
      short8_t a[4], b[4];
#pragma unroll
      for (int mi = 0; mi < 4; ++mi)
        a[mi] = *(const short8_t*)&smA[buf][(wm * 64 + mi * 16 + l15) * LDP + (ks * 4 + hi) * 8];
#pragma unroll
      for (int ni = 0; ni < 4; ++ni)
        b[ni] = *(const short8_t*)&smB[buf][(wn * 64 + ni * 16 + l15) * LDP + (ks * 4 + hi) * 8];
#pragma unroll
      for (int mi = 0; mi < 4; ++mi)
#pragma unroll
        for (int ni = 0; ni < 4; ++ni)
          acc[mi][ni] = __builtin_amdgcn_mfma_f32_16x16x32_bf16(a[mi], b[ni], acc[mi][ni], 0, 0, 0);
    }
  };

  const int KT = H_ / BK;  // 16

  // prologue: tile0 -> buf0; tile1 -> Y regs (in flight)
  LOADSET(X, 0);
  WRITESET(X, 0);
  LOADSET(Y, 1);
  __syncthreads();   // one-time full drain

  for (int kt = 0; kt < KT; kt += 2) {
    compute(0);                         // tile kt
    if (kt + 2 < KT) LOADSET(X, kt + 2);   // in flight across barrier (counted wait)
    WRITESET(Y, 1);                     // tile kt+1 -> buf1 (waits Y only)
    FENCE_BAR();
    compute(1);                         // tile kt+1
    if (kt + 3 < KT) LOADSET(Y, kt + 3);
    if (kt + 2 < KT) WRITESET(X, 0);    // tile kt+2 -> buf0
    FENCE_BAR();
  }

  const int colb = nt * BN + wn * 64;
  if constexpr (EPI == 0) {
#pragma unroll
    for (int ni = 0; ni < 4; ++ni) {
      const int col = colb + ni * 16 + l15;
      const float bv = bias[e * H_ + col];
#pragma unroll
      for (int mi = 0; mi < 4; ++mi)
#pragma unroll
        for (int r = 0; r < 4; ++r) {
          const int lr = wm * 64 + mi * 16 + hi * 4 + r;
          if (mt * BM + lr < count) {
            float v = acc[mi][ni][r] + bv;
            h1out[(Arow0 + lr) * H_ + col] = __float2bfloat16(fmaxf(v, 0.f));
          }
        }
    }
  } else {
#pragma unroll
    for (int mi = 0; mi < 4; ++mi)
#pragma unroll
      for (int r = 0; r < 4; ++r) {
        const int lr = wm * 64 + mi * 16 + hi * 4 + r;
        if (mt * BM + lr < count) {
          const int p = (int)Arow0 + lr;
          const int t = tok[p];
          const float w = wsl[p];
#pragma unroll
          for (int ni = 0; ni < 4; ++ni) {
            const int col = colb + ni * 16 + l15;
            float v = (acc[mi][ni][r] + bias[e * H_ + col]) * w;
            atomicAdd(out + (size_t)t * H_ + col, v);
          }
        }
      }
  }
#undef LOADSET
#undef WRITESET
}

// ---------------------------------------------------------------------------
extern "C" void kernel_launch(void* const* d_in, const int* in_sizes, int n_in,
                              void* d_out, int out_size, void* d_ws, size_t ws_size,
                              hipStream_t stream) {
  const float* x   = (const float*)d_in[0];
  const int*   idx = (const int*)d_in[1];
  const float* tkw = (const float*)d_in[2];
  const float* w1  = (const float*)d_in[3];
  const float* b1  = (const float*)d_in[4];
  const float* w2  = (const float*)d_in[5];
  const float* b2  = (const float*)d_in[6];
  float* out = (float*)d_out;

  uint8_t* ws = (uint8_t*)d_ws;
  int*   cnt  = (int*)(ws + CNT_OFF);
  int*   cur  = (int*)(ws + CUR_OFF);
  int*   offs = (int*)(ws + OFFS_OFF);
  int*   toff = (int*)(ws + TOFF_OFF);
  int*   tok  = (int*)(ws + TOK_OFF);
  float* wsl  = (float*)(ws + WSL_OFF);
  __hip_bfloat16* h1  = (__hip_bfloat16*)(ws + H1_OFF);
  __hip_bfloat16* w1t = (__hip_bfloat16*)(ws + W1T_OFF);
  __hip_bfloat16* w2t = (__hip_bfloat16*)(ws + W2T_OFF);

  hipMemsetAsync(ws, 0, 1024, stream);
  hipMemsetAsync(d_out, 0, (size_t)out_size * sizeof(float), stream);

  transpose_cast<<<dim3(H_ / 32, H_ / 32, 2 * E_), dim3(32, 8), 0, stream>>>(w1, w2, w1t, w2t);

  route_count<<<NSLOT / 256, 256, 0, stream>>>(idx, cnt);
  route_scan<<<1, 64, 0, stream>>>(cnt, offs, cur, toff);
  route_scatter<<<NSLOT / 256, 256, 0, stream>>>(idx, tkw, cur, tok, wsl);

  moe_gemm<0><<<NWG, 256, 0, stream>>>(x, nullptr, w1t, b1, h1, nullptr,
                                       cnt, offs, toff, tok, wsl);
  moe_gemm<1><<<NWG, 256, 0, stream>>>(nullptr, h1, w2t, b2, nullptr, out,
                                       cnt, offs, toff, tok, wsl);
}